// Round 9
// baseline (150.363 us; speedup 1.0000x reference)
//
#include <hip/hip_runtime.h>
#include <math.h>

#define NPTS 4096
#define BLK 256
#define PAIR_BLOCKS 4096
#define EV_BLOCKS 1024
#define TOTAL_BLOCKS (PAIR_BLOCKS + EV_BLOCKS)   // 5120; every 5th block is an ev block
#define VB 4                                     // ILP batch width
#define CNT_OFF (TOTAL_BLOCKS * 4)               // byte offset of counter in d_ws

// ---------------- block-level float reduction (deterministic; result in thread 0) ----
__device__ __forceinline__ float block_reduce_f(float v) {
    #pragma unroll
    for (int off = 32; off > 0; off >>= 1)
        v += __shfl_down(v, off, 64);
    __shared__ float smem[BLK / 64];
    const int lane = threadIdx.x & 63;
    const int wid  = threadIdx.x >> 6;
    if (lane == 0) smem[wid] = v;
    __syncthreads();
    float t = 0.f;
    if (threadIdx.x == 0) {
        #pragma unroll
        for (int w = 0; w < BLK / 64; ++w) t += smem[w];
    }
    return t;
}

// ---------------- fused kernel: pair integral + event intensity; last block combines --
__global__ __launch_bounds__(BLK) void fused_kernel(
        const int* __restrict__ eu, const int* __restrict__ ev,
        const float* __restrict__ et,
        const float2* __restrict__ z0, const float2* __restrict__ v0,
        const float* __restrict__ beta_p, const float* __restrict__ t0_p,
        const float* __restrict__ tn_p,
        float* __restrict__ partial, unsigned* __restrict__ cnt,
        float* __restrict__ out, int nE) {
    const int bid = blockIdx.x;
    const float b = beta_p[0];
    float acc = 0.f;

    if (bid % 5 == 0) {
        // ----- event part: sum_e ||dz + dv*t||^2 (identical to R7) -----
        const int ev_id = bid / 5;                       // [0, EV_BLOCKS)
        for (int i = ev_id * BLK + threadIdx.x; i < nE; i += EV_BLOCKS * BLK) {
            const int a = eu[i];
            const int bw = ev[i];
            const float t = et[i];
            const float2 za = z0[a], zb = z0[bw];
            const float2 va = v0[a], vb = v0[bw];
            const float dx = fmaf(va.x - vb.x, t, za.x - zb.x);
            const float dy = fmaf(va.y - vb.y, t, za.y - zb.y);
            acc += fmaf(dx, dx, dy * dy);
        }
    } else {
        // ----- pair part: each unordered pair exactly once; V=4 stage-batched ILP ----
        const int pair_id = bid - (bid / 5 + 1);         // [0, PAIR_BLOCKS)
        const float t0 = t0_p[0];
        const float tn = tn_p[0];
        const float C  = -0.88622692545275801365f * __expf(b);   // -sqrt(pi)/2 * e^b

        const int tid0 = pair_id * BLK + threadIdx.x;    // idx for it=0; stride 2^20 per it
        const int j    = tid0 & (NPTS - 1);              // fixed per thread
        const int i0   = tid0 >> 12;                     // [0, 256); i = i0 + it*256
        const int jf   = NPTS - 1 - j;
        const float2 zj  = z0[j],  vj  = v0[j];
        const float2 zjf = z0[jf], vjf = v0[jf];

        #pragma unroll
        for (int half = 0; half < 2; ++half) {
            // ---- stage 1: coords, loads, operand assembly (4 independent cells) ----
            float a[VB], bbv[VB], m[VB], n[VB];
            bool  ok[VB];
            #pragma unroll
            for (int k = 0; k < VB; ++k) {
                const int it = half * VB + k;
                const int i  = i0 + it * 256;            // block-uniform value
                const bool fold = (j < i);               // per-lane
                ok[k] = (j != i);
                const int ii = fold ? (NPTS - 1 - i) : i;
                const float2 zi = z0[ii];
                const float2 vi = v0[ii];
                a[k]   = zi.x - (fold ? zjf.x : zj.x);
                bbv[k] = zi.y - (fold ? zjf.y : zj.y);
                m[k]   = vi.x - (fold ? vjf.x : vj.x);
                n[k]   = vi.y - (fold ? vjf.y : vj.y);
            }
            // ---- stage 2: batched algebra ----
            float s2[VB], inv_s[VB], am[VB], q[VB];
            #pragma unroll
            for (int k = 0; k < VB; ++k) s2[k] = fmaf(m[k], m[k], n[k] * n[k]);
            #pragma unroll
            for (int k = 0; k < VB; ++k) inv_s[k] = __builtin_amdgcn_rsqf(s2[k]);
            #pragma unroll
            for (int k = 0; k < VB; ++k) am[k] = fmaf(a[k], m[k], bbv[k] * n[k]);
            #pragma unroll
            for (int k = 0; k < VB; ++k) q[k] = fmaf(bbv[k], m[k], -a[k] * n[k]) * inv_s[k];
            // ---- stage 3: batched erf args ----
            float x1[VB], x2[VB];
            #pragma unroll
            for (int k = 0; k < VB; ++k) x1[k] = fmaf(s2[k], t0, am[k]) * inv_s[k];
            #pragma unroll
            for (int k = 0; k < VB; ++k) x2[k] = fmaf(s2[k], tn, am[k]) * inv_s[k];
            // ---- stage 4: batched fast_erf (A&S 7.1.26) for x1, x2 ----
            float t1[VB], t2[VB], g1[VB], g2[VB];
            #pragma unroll
            for (int k = 0; k < VB; ++k) t1[k] = __builtin_amdgcn_rcpf(fmaf(0.3275911f, fabsf(x1[k]), 1.0f));
            #pragma unroll
            for (int k = 0; k < VB; ++k) t2[k] = __builtin_amdgcn_rcpf(fmaf(0.3275911f, fabsf(x2[k]), 1.0f));
            #pragma unroll
            for (int k = 0; k < VB; ++k) g1[k] = __expf(-x1[k] * x1[k]);
            #pragma unroll
            for (int k = 0; k < VB; ++k) g2[k] = __expf(-x2[k] * x2[k]);
            float e1[VB], e2[VB];
            #pragma unroll
            for (int k = 0; k < VB; ++k) {
                float p = fmaf(t1[k], 1.061405429f, -1.453152027f);
                p = fmaf(t1[k], p, 1.421413741f);
                p = fmaf(t1[k], p, -0.284496736f);
                p = fmaf(t1[k], p, 0.254829592f);
                p *= t1[k];
                e1[k] = copysignf(fmaf(-p, g1[k], 1.0f), x1[k]);
            }
            #pragma unroll
            for (int k = 0; k < VB; ++k) {
                float p = fmaf(t2[k], 1.061405429f, -1.453152027f);
                p = fmaf(t2[k], p, 1.421413741f);
                p = fmaf(t2[k], p, -0.284496736f);
                p = fmaf(t2[k], p, 0.254829592f);
                p *= t2[k];
                e2[k] = copysignf(fmaf(-p, g2[k], 1.0f), x2[k]);
            }
            // ---- stage 5: Gaussian factor + masked accumulate (select kills diag NaN) --
            float E[VB];
            #pragma unroll
            for (int k = 0; k < VB; ++k) E[k] = __expf(-q[k] * q[k]);
            #pragma unroll
            for (int k = 0; k < VB; ++k) {
                const float contrib = (C * E[k]) * (e1[k] - e2[k]) * inv_s[k];
                acc += ok[k] ? contrib : 0.f;
            }
        }
    }

    // ----- block reduce + last-block deterministic combine -----
    const float r = block_reduce_f(acc);
    __shared__ bool amLast;
    if (threadIdx.x == 0) {
        __hip_atomic_store(&partial[bid], r, __ATOMIC_RELEASE, __HIP_MEMORY_SCOPE_AGENT);
        const unsigned old = __hip_atomic_fetch_add(cnt, 1u, __ATOMIC_ACQ_REL,
                                                    __HIP_MEMORY_SCOPE_AGENT);
        amLast = (old == TOTAL_BLOCKS - 1);
    }
    __syncthreads();

    if (amLast) {
        __shared__ double sd[BLK];
        double s = 0.0;
        #pragma unroll
        for (int k = 0; k < TOTAL_BLOCKS / BLK; ++k)   // 20 fixed-order slots/thread
            s += (double)__hip_atomic_load(&partial[threadIdx.x + k * BLK],
                                           __ATOMIC_RELAXED, __HIP_MEMORY_SCOPE_AGENT);
        sd[threadIdx.x] = s;
        __syncthreads();
        for (int st = BLK / 2; st > 0; st >>= 1) {
            if (threadIdx.x < st) sd[threadIdx.x] += sd[threadIdx.x + st];
            __syncthreads();
        }
        if (threadIdx.x == 0)
            out[0] = (float)((double)nE * (double)b - sd[0]);
    }
}

extern "C" void kernel_launch(void* const* d_in, const int* in_sizes, int n_in,
                              void* d_out, int out_size, void* d_ws, size_t ws_size,
                              hipStream_t stream) {
    const int*    eu   = (const int*)d_in[0];
    const int*    ev   = (const int*)d_in[1];
    const float*  et   = (const float*)d_in[2];
    const float*  t0   = (const float*)d_in[3];
    const float*  tn   = (const float*)d_in[4];
    const float*  beta = (const float*)d_in[5];
    const float2* z0   = (const float2*)d_in[6];
    const float2* v0   = (const float2*)d_in[7];
    float* out = (float*)d_out;
    const int nE = in_sizes[0];

    float*    partial = (float*)d_ws;                      // TOTAL_BLOCKS floats
    unsigned* cnt     = (unsigned*)((char*)d_ws + CNT_OFF);

    hipMemsetAsync((void*)cnt, 0, sizeof(unsigned), stream);
    fused_kernel<<<TOTAL_BLOCKS, BLK, 0, stream>>>(eu, ev, et, z0, v0, beta, t0, tn,
                                                   partial, cnt, out, nE);
}

// Round 10
// 28.261 us; speedup vs baseline: 5.3205x; 5.3205x over previous
//
#include <hip/hip_runtime.h>
#include <math.h>

#define NPTS 4096
#define BLK 256
#define PAIR_BLOCKS 4096
#define EV_BLOCKS 1024
#define TOTAL_BLOCKS (PAIR_BLOCKS + EV_BLOCKS)   // 5120; every 5th block is an ev block
#define VB 4                                     // ILP batch width

// ---------------- block-level float reduction (deterministic) ----------------
__device__ __forceinline__ float block_reduce_f(float v) {
    #pragma unroll
    for (int off = 32; off > 0; off >>= 1)
        v += __shfl_down(v, off, 64);
    __shared__ float smem[BLK / 64];
    const int lane = threadIdx.x & 63;
    const int wid  = threadIdx.x >> 6;
    if (lane == 0) smem[wid] = v;
    __syncthreads();
    float t = 0.f;
    if (threadIdx.x == 0) {
        #pragma unroll
        for (int w = 0; w < BLK / 64; ++w) t += smem[w];
    }
    return t;  // valid in thread 0 only
}

// ---------------- fused kernel: pair integral + event intensity ----------------
__global__ __launch_bounds__(BLK) void fused_kernel(
        const int* __restrict__ eu, const int* __restrict__ ev,
        const float* __restrict__ et,
        const float2* __restrict__ z0, const float2* __restrict__ v0,
        const float* __restrict__ beta_p, const float* __restrict__ t0_p,
        const float* __restrict__ tn_p,
        float* __restrict__ ev_partials, float* __restrict__ pair_partials,
        int nE) {
    const int bid = blockIdx.x;
    const bool is_ev = (bid % 5 == 0);

    if (is_ev) {
        // ----- event part: sum_e ||dz + dv*t||^2 (identical to R7) -----
        const int ev_id = bid / 5;                       // [0, EV_BLOCKS)
        float acc = 0.f;
        for (int i = ev_id * BLK + threadIdx.x; i < nE; i += EV_BLOCKS * BLK) {
            const int a = eu[i];
            const int bw = ev[i];
            const float t = et[i];
            const float2 za = z0[a], zb = z0[bw];
            const float2 va = v0[a], vb = v0[bw];
            const float dx = fmaf(va.x - vb.x, t, za.x - zb.x);
            const float dy = fmaf(va.y - vb.y, t, za.y - zb.y);
            acc += fmaf(dx, dx, dy * dy);
        }
        const float r = block_reduce_f(acc);
        if (threadIdx.x == 0) ev_partials[ev_id] = r;
    } else {
        // ----- pair part: each unordered pair exactly once; V=4 stage-batched ILP ----
        const int pair_id = bid - (bid / 5 + 1);         // [0, PAIR_BLOCKS)
        const float b  = beta_p[0];
        const float t0 = t0_p[0];
        const float tn = tn_p[0];
        const float C  = -0.88622692545275801365f * __expf(b);   // -sqrt(pi)/2 * e^b

        // PROVABLY-uniform i (blockIdx-only); same values as (pair_id*256+tid)>>12
        const int i0 = pair_id >> 4;                     // [0, 256); block-uniform
        const int j  = ((pair_id & 15) << 8) | threadIdx.x;  // per-lane, coalesced
        const int jf = NPTS - 1 - j;
        const float2 zj  = z0[j],  vj  = v0[j];
        const float2 zjf = z0[jf], vjf = v0[jf];

        float acc = 0.f;
        #pragma unroll
        for (int half = 0; half < 2; ++half) {
            // ---- stage 1: scalar-broadcast i-side loads + per-lane select ----
            float a[VB], bbv[VB], m[VB], n[VB];
            bool  ok[VB];
            #pragma unroll
            for (int k = 0; k < VB; ++k) {
                const int it = half * VB + k;
                const int i  = i0 + it * 256;            // block-uniform (blockIdx-only)
                const float2 ziA = z0[i];                // s_load broadcast
                const float2 ziB = z0[NPTS - 1 - i];     // s_load broadcast
                const float2 viA = v0[i];
                const float2 viB = v0[NPTS - 1 - i];
                const bool fold = (j < i);               // per-lane
                ok[k] = (j != i);
                const float zix = fold ? ziB.x : ziA.x;
                const float ziy = fold ? ziB.y : ziA.y;
                const float vix = fold ? viB.x : viA.x;
                const float viy = fold ? viB.y : viA.y;
                a[k]   = zix - (fold ? zjf.x : zj.x);
                bbv[k] = ziy - (fold ? zjf.y : zj.y);
                m[k]   = vix - (fold ? vjf.x : vj.x);
                n[k]   = viy - (fold ? vjf.y : vj.y);
            }
            // ---- stage 2: batched algebra ----
            float s2[VB], inv_s[VB], am[VB], q[VB];
            #pragma unroll
            for (int k = 0; k < VB; ++k) s2[k] = fmaf(m[k], m[k], n[k] * n[k]);
            #pragma unroll
            for (int k = 0; k < VB; ++k) inv_s[k] = __builtin_amdgcn_rsqf(s2[k]);
            #pragma unroll
            for (int k = 0; k < VB; ++k) am[k] = fmaf(a[k], m[k], bbv[k] * n[k]);
            #pragma unroll
            for (int k = 0; k < VB; ++k) q[k] = fmaf(bbv[k], m[k], -a[k] * n[k]) * inv_s[k];
            // ---- stage 3: batched erf args ----
            float x1[VB], x2[VB];
            #pragma unroll
            for (int k = 0; k < VB; ++k) x1[k] = fmaf(s2[k], t0, am[k]) * inv_s[k];
            #pragma unroll
            for (int k = 0; k < VB; ++k) x2[k] = fmaf(s2[k], tn, am[k]) * inv_s[k];
            // ---- stage 4: batched fast_erf (A&S 7.1.26, |err|<=1.5e-7) ----
            float t1[VB], t2[VB], g1[VB], g2[VB];
            #pragma unroll
            for (int k = 0; k < VB; ++k) t1[k] = __builtin_amdgcn_rcpf(fmaf(0.3275911f, fabsf(x1[k]), 1.0f));
            #pragma unroll
            for (int k = 0; k < VB; ++k) t2[k] = __builtin_amdgcn_rcpf(fmaf(0.3275911f, fabsf(x2[k]), 1.0f));
            #pragma unroll
            for (int k = 0; k < VB; ++k) g1[k] = __expf(-x1[k] * x1[k]);
            #pragma unroll
            for (int k = 0; k < VB; ++k) g2[k] = __expf(-x2[k] * x2[k]);
            float e1[VB], e2[VB];
            #pragma unroll
            for (int k = 0; k < VB; ++k) {
                float p = fmaf(t1[k], 1.061405429f, -1.453152027f);
                p = fmaf(t1[k], p, 1.421413741f);
                p = fmaf(t1[k], p, -0.284496736f);
                p = fmaf(t1[k], p, 0.254829592f);
                p *= t1[k];
                e1[k] = copysignf(fmaf(-p, g1[k], 1.0f), x1[k]);
            }
            #pragma unroll
            for (int k = 0; k < VB; ++k) {
                float p = fmaf(t2[k], 1.061405429f, -1.453152027f);
                p = fmaf(t2[k], p, 1.421413741f);
                p = fmaf(t2[k], p, -0.284496736f);
                p = fmaf(t2[k], p, 0.254829592f);
                p *= t2[k];
                e2[k] = copysignf(fmaf(-p, g2[k], 1.0f), x2[k]);
            }
            // ---- stage 5: Gaussian factor + masked accumulate (select kills diag NaN) --
            float E[VB];
            #pragma unroll
            for (int k = 0; k < VB; ++k) E[k] = __expf(-q[k] * q[k]);
            #pragma unroll
            for (int k = 0; k < VB; ++k) {
                const float contrib = (C * E[k]) * (e1[k] - e2[k]) * inv_s[k];
                acc += ok[k] ? contrib : 0.f;
            }
        }
        const float r = block_reduce_f(acc);
        if (threadIdx.x == 0) pair_partials[pair_id] = r;
    }
}

// ---------------- final combine (double precision, deterministic) ----------------
__global__ void final_kernel(const float* __restrict__ evp, const float* __restrict__ pp,
                             const float* __restrict__ beta_p, float* __restrict__ out,
                             int nE) {
    __shared__ double sd[BLK];
    double se = 0.0;
    for (int i = threadIdx.x; i < EV_BLOCKS; i += BLK) se += (double)evp[i];
    double sp = 0.0;
    for (int i = threadIdx.x; i < PAIR_BLOCKS; i += BLK) sp += (double)pp[i];
    sd[threadIdx.x] = se + sp;   // (sum d2) + non_event_intensity
    __syncthreads();
    for (int s = BLK / 2; s > 0; s >>= 1) {
        if (threadIdx.x < s) sd[threadIdx.x] += sd[threadIdx.x + s];
        __syncthreads();
    }
    if (threadIdx.x == 0) {
        out[0] = (float)((double)nE * (double)beta_p[0] - sd[0]);
    }
}

extern "C" void kernel_launch(void* const* d_in, const int* in_sizes, int n_in,
                              void* d_out, int out_size, void* d_ws, size_t ws_size,
                              hipStream_t stream) {
    const int*    eu   = (const int*)d_in[0];
    const int*    ev   = (const int*)d_in[1];
    const float*  et   = (const float*)d_in[2];
    const float*  t0   = (const float*)d_in[3];
    const float*  tn   = (const float*)d_in[4];
    const float*  beta = (const float*)d_in[5];
    const float2* z0   = (const float2*)d_in[6];
    const float2* v0   = (const float2*)d_in[7];
    float* out = (float*)d_out;
    const int nE = in_sizes[0];

    float* ev_partials   = (float*)d_ws;                  // EV_BLOCKS floats
    float* pair_partials = ev_partials + EV_BLOCKS;       // PAIR_BLOCKS floats

    fused_kernel<<<TOTAL_BLOCKS, BLK, 0, stream>>>(eu, ev, et, z0, v0, beta, t0, tn,
                                                   ev_partials, pair_partials, nE);
    final_kernel<<<1, BLK, 0, stream>>>(ev_partials, pair_partials, beta, out, nE);
}

// Round 11
// 28.150 us; speedup vs baseline: 5.3414x; 1.0039x over previous
//
#include <hip/hip_runtime.h>
#include <math.h>

#define NPTS 4096
#define BLK 256
#define PAIR_BLOCKS 4096
#define EV_BLOCKS 1024
#define TOTAL_BLOCKS (PAIR_BLOCKS + EV_BLOCKS)   // 5120; every 5th block is an ev block
#define VB 8                                     // ILP batch width (8 chains/thread)

// ---------------- block-level float reduction (deterministic) ----------------
__device__ __forceinline__ float block_reduce_f(float v) {
    #pragma unroll
    for (int off = 32; off > 0; off >>= 1)
        v += __shfl_down(v, off, 64);
    __shared__ float smem[BLK / 64];
    const int lane = threadIdx.x & 63;
    const int wid  = threadIdx.x >> 6;
    if (lane == 0) smem[wid] = v;
    __syncthreads();
    float t = 0.f;
    if (threadIdx.x == 0) {
        #pragma unroll
        for (int w = 0; w < BLK / 64; ++w) t += smem[w];
    }
    return t;  // valid in thread 0 only
}

// ---------------- fused kernel: pair integral + event intensity ----------------
__global__ __launch_bounds__(BLK) void fused_kernel(
        const int* __restrict__ eu, const int* __restrict__ ev,
        const float* __restrict__ et,
        const float2* __restrict__ z0, const float2* __restrict__ v0,
        const float* __restrict__ beta_p, const float* __restrict__ t0_p,
        const float* __restrict__ tn_p,
        float* __restrict__ ev_partials, float* __restrict__ pair_partials,
        int nE) {
    const int bid = blockIdx.x;
    const bool is_ev = (bid % 5 == 0);

    if (is_ev) {
        // ----- event part: sum_e ||dz + dv*t||^2 (identical to R7/R10) -----
        const int ev_id = bid / 5;                       // [0, EV_BLOCKS)
        float acc = 0.f;
        for (int i = ev_id * BLK + threadIdx.x; i < nE; i += EV_BLOCKS * BLK) {
            const int a = eu[i];
            const int bw = ev[i];
            const float t = et[i];
            const float2 za = z0[a], zb = z0[bw];
            const float2 va = v0[a], vb = v0[bw];
            const float dx = fmaf(va.x - vb.x, t, za.x - zb.x);
            const float dy = fmaf(va.y - vb.y, t, za.y - zb.y);
            acc += fmaf(dx, dx, dy * dy);
        }
        const float r = block_reduce_f(acc);
        if (threadIdx.x == 0) ev_partials[ev_id] = r;
    } else {
        // ----- pair part: each unordered pair exactly once; VB=8 stage-batched ILP ----
        const int pair_id = bid - (bid / 5 + 1);         // [0, PAIR_BLOCKS)
        const float b  = beta_p[0];
        const float t0 = t0_p[0];
        const float tn = tn_p[0];
        const float C  = -0.88622692545275801365f * __expf(b);   // -sqrt(pi)/2 * e^b

        // PROVABLY-uniform i (blockIdx-only); j per-lane, coalesced
        const int i0 = pair_id >> 4;                     // [0, 256); block-uniform
        const int j  = ((pair_id & 15) << 8) | threadIdx.x;
        const int jf = NPTS - 1 - j;
        const float2 zj  = z0[j],  vj  = v0[j];
        const float2 zjf = z0[jf], vjf = v0[jf];

        float acc = 0.f;
        {
            // ---- stage 1: scalar-broadcast i-side loads + per-lane select ----
            float a[VB], bbv[VB], m[VB], n[VB];
            bool  ok[VB];
            #pragma unroll
            for (int k = 0; k < VB; ++k) {
                const int i  = i0 + k * 256;             // block-uniform (blockIdx-only)
                const float2 ziA = z0[i];                // s_load broadcast
                const float2 ziB = z0[NPTS - 1 - i];     // s_load broadcast
                const float2 viA = v0[i];
                const float2 viB = v0[NPTS - 1 - i];
                const bool fold = (j < i);               // per-lane
                ok[k] = (j != i);
                const float zix = fold ? ziB.x : ziA.x;
                const float ziy = fold ? ziB.y : ziA.y;
                const float vix = fold ? viB.x : viA.x;
                const float viy = fold ? viB.y : viA.y;
                a[k]   = zix - (fold ? zjf.x : zj.x);
                bbv[k] = ziy - (fold ? zjf.y : zj.y);
                m[k]   = vix - (fold ? vjf.x : vj.x);
                n[k]   = viy - (fold ? vjf.y : vj.y);
            }
            // ---- stage 2: batched algebra ----
            float s2[VB], inv_s[VB], am[VB], q[VB];
            #pragma unroll
            for (int k = 0; k < VB; ++k) s2[k] = fmaf(m[k], m[k], n[k] * n[k]);
            #pragma unroll
            for (int k = 0; k < VB; ++k) inv_s[k] = __builtin_amdgcn_rsqf(s2[k]);
            #pragma unroll
            for (int k = 0; k < VB; ++k) am[k] = fmaf(a[k], m[k], bbv[k] * n[k]);
            #pragma unroll
            for (int k = 0; k < VB; ++k) q[k] = fmaf(bbv[k], m[k], -a[k] * n[k]) * inv_s[k];
            // ---- stage 3: batched erf args ----
            float x1[VB], x2[VB];
            #pragma unroll
            for (int k = 0; k < VB; ++k) x1[k] = fmaf(s2[k], t0, am[k]) * inv_s[k];
            #pragma unroll
            for (int k = 0; k < VB; ++k) x2[k] = fmaf(s2[k], tn, am[k]) * inv_s[k];
            // ---- stage 4: batched fast_erf (A&S 7.1.26, |err|<=1.5e-7) ----
            float t1[VB], t2[VB], g1[VB], g2[VB];
            #pragma unroll
            for (int k = 0; k < VB; ++k) t1[k] = __builtin_amdgcn_rcpf(fmaf(0.3275911f, fabsf(x1[k]), 1.0f));
            #pragma unroll
            for (int k = 0; k < VB; ++k) t2[k] = __builtin_amdgcn_rcpf(fmaf(0.3275911f, fabsf(x2[k]), 1.0f));
            #pragma unroll
            for (int k = 0; k < VB; ++k) g1[k] = __expf(-x1[k] * x1[k]);
            #pragma unroll
            for (int k = 0; k < VB; ++k) g2[k] = __expf(-x2[k] * x2[k]);
            float e1[VB], e2[VB];
            #pragma unroll
            for (int k = 0; k < VB; ++k) {
                float p = fmaf(t1[k], 1.061405429f, -1.453152027f);
                p = fmaf(t1[k], p, 1.421413741f);
                p = fmaf(t1[k], p, -0.284496736f);
                p = fmaf(t1[k], p, 0.254829592f);
                p *= t1[k];
                e1[k] = copysignf(fmaf(-p, g1[k], 1.0f), x1[k]);
            }
            #pragma unroll
            for (int k = 0; k < VB; ++k) {
                float p = fmaf(t2[k], 1.061405429f, -1.453152027f);
                p = fmaf(t2[k], p, 1.421413741f);
                p = fmaf(t2[k], p, -0.284496736f);
                p = fmaf(t2[k], p, 0.254829592f);
                p *= t2[k];
                e2[k] = copysignf(fmaf(-p, g2[k], 1.0f), x2[k]);
            }
            // ---- stage 5: Gaussian factor + masked accumulate (select kills diag NaN) --
            float E[VB];
            #pragma unroll
            for (int k = 0; k < VB; ++k) E[k] = __expf(-q[k] * q[k]);
            #pragma unroll
            for (int k = 0; k < VB; ++k) {
                const float contrib = (C * E[k]) * (e1[k] - e2[k]) * inv_s[k];
                acc += ok[k] ? contrib : 0.f;
            }
        }
        const float r = block_reduce_f(acc);
        if (threadIdx.x == 0) pair_partials[pair_id] = r;
    }
}

// ---------------- final combine (double precision, deterministic) ----------------
__global__ void final_kernel(const float* __restrict__ evp, const float* __restrict__ pp,
                             const float* __restrict__ beta_p, float* __restrict__ out,
                             int nE) {
    __shared__ double sd[BLK];
    double se = 0.0;
    for (int i = threadIdx.x; i < EV_BLOCKS; i += BLK) se += (double)evp[i];
    double sp = 0.0;
    for (int i = threadIdx.x; i < PAIR_BLOCKS; i += BLK) sp += (double)pp[i];
    sd[threadIdx.x] = se + sp;   // (sum d2) + non_event_intensity
    __syncthreads();
    for (int s = BLK / 2; s > 0; s >>= 1) {
        if (threadIdx.x < s) sd[threadIdx.x] += sd[threadIdx.x + s];
        __syncthreads();
    }
    if (threadIdx.x == 0) {
        out[0] = (float)((double)nE * (double)beta_p[0] - sd[0]);
    }
}

extern "C" void kernel_launch(void* const* d_in, const int* in_sizes, int n_in,
                              void* d_out, int out_size, void* d_ws, size_t ws_size,
                              hipStream_t stream) {
    const int*    eu   = (const int*)d_in[0];
    const int*    ev   = (const int*)d_in[1];
    const float*  et   = (const float*)d_in[2];
    const float*  t0   = (const float*)d_in[3];
    const float*  tn   = (const float*)d_in[4];
    const float*  beta = (const float*)d_in[5];
    const float2* z0   = (const float2*)d_in[6];
    const float2* v0   = (const float2*)d_in[7];
    float* out = (float*)d_out;
    const int nE = in_sizes[0];

    float* ev_partials   = (float*)d_ws;                  // EV_BLOCKS floats
    float* pair_partials = ev_partials + EV_BLOCKS;       // PAIR_BLOCKS floats

    fused_kernel<<<TOTAL_BLOCKS, BLK, 0, stream>>>(eu, ev, et, z0, v0, beta, t0, tn,
                                                   ev_partials, pair_partials, nE);
    final_kernel<<<1, BLK, 0, stream>>>(ev_partials, pair_partials, beta, out, nE);
}

// Round 12
// 26.357 us; speedup vs baseline: 5.7048x; 1.0680x over previous
//
#include <hip/hip_runtime.h>
#include <math.h>

#define NPTS 4096
#define BLK 256
#define PAIR_BLOCKS 4352   // sum_{jg=0}^{15} 32*(jg+1): upper-triangle 8x256 tiles
#define EV_BLOCKS 1088
#define TOTAL_BLOCKS 5440  // pair:ev = 4:1; every 5th block is an ev block
#define VB 8               // i-values per block (consecutive, block-uniform)

// ---------------- block-level float reduction (deterministic) ----------------
__device__ __forceinline__ float block_reduce_f(float v) {
    #pragma unroll
    for (int off = 32; off > 0; off >>= 1)
        v += __shfl_down(v, off, 64);
    __shared__ float smem[BLK / 64];
    const int lane = threadIdx.x & 63;
    const int wid  = threadIdx.x >> 6;
    if (lane == 0) smem[wid] = v;
    __syncthreads();
    float t = 0.f;
    if (threadIdx.x == 0) {
        #pragma unroll
        for (int w = 0; w < BLK / 64; ++w) t += smem[w];
    }
    return t;  // valid in thread 0 only
}

// ---------------- pair tile body: 8 uniform i x 256 lane j; MIXED masks i<j ----
template<bool MIXED>
__device__ __forceinline__ float pair_body(const float2* __restrict__ z0,
                                           const float2* __restrict__ v0,
                                           int ibase, int j,
                                           float t0, float tn, float C) {
    const float2 zj = z0[j], vj = v0[j];   // per-lane, coalesced, hoisted

    // ---- stage 1: pure subtracts (i-side is SGPR via uniform s_load) ----
    float a[VB], bbv[VB], m[VB], n[VB];
    #pragma unroll
    for (int k = 0; k < VB; ++k) {
        const float2 zi = z0[ibase + k];   // block-uniform -> s_load broadcast
        const float2 vi = v0[ibase + k];
        a[k]   = zi.x - zj.x;
        bbv[k] = zi.y - zj.y;
        m[k]   = vi.x - vj.x;
        n[k]   = vi.y - vj.y;
    }
    // ---- stage 2: batched algebra ----
    float s2[VB], inv_s[VB], am[VB], q[VB];
    #pragma unroll
    for (int k = 0; k < VB; ++k) s2[k] = fmaf(m[k], m[k], n[k] * n[k]);
    #pragma unroll
    for (int k = 0; k < VB; ++k) inv_s[k] = __builtin_amdgcn_rsqf(s2[k]);
    #pragma unroll
    for (int k = 0; k < VB; ++k) am[k] = fmaf(a[k], m[k], bbv[k] * n[k]);
    #pragma unroll
    for (int k = 0; k < VB; ++k) q[k] = fmaf(bbv[k], m[k], -a[k] * n[k]) * inv_s[k];
    // ---- stage 3: batched erf args ----
    float x1[VB], x2[VB];
    #pragma unroll
    for (int k = 0; k < VB; ++k) x1[k] = fmaf(s2[k], t0, am[k]) * inv_s[k];
    #pragma unroll
    for (int k = 0; k < VB; ++k) x2[k] = fmaf(s2[k], tn, am[k]) * inv_s[k];
    // ---- stage 4: batched fast_erf (A&S 7.1.26, |err|<=1.5e-7) ----
    float t1[VB], t2[VB], g1[VB], g2[VB];
    #pragma unroll
    for (int k = 0; k < VB; ++k) t1[k] = __builtin_amdgcn_rcpf(fmaf(0.3275911f, fabsf(x1[k]), 1.0f));
    #pragma unroll
    for (int k = 0; k < VB; ++k) t2[k] = __builtin_amdgcn_rcpf(fmaf(0.3275911f, fabsf(x2[k]), 1.0f));
    #pragma unroll
    for (int k = 0; k < VB; ++k) g1[k] = __expf(-x1[k] * x1[k]);
    #pragma unroll
    for (int k = 0; k < VB; ++k) g2[k] = __expf(-x2[k] * x2[k]);
    float e1[VB], e2[VB];
    #pragma unroll
    for (int k = 0; k < VB; ++k) {
        float p = fmaf(t1[k], 1.061405429f, -1.453152027f);
        p = fmaf(t1[k], p, 1.421413741f);
        p = fmaf(t1[k], p, -0.284496736f);
        p = fmaf(t1[k], p, 0.254829592f);
        p *= t1[k];
        e1[k] = copysignf(fmaf(-p, g1[k], 1.0f), x1[k]);
    }
    #pragma unroll
    for (int k = 0; k < VB; ++k) {
        float p = fmaf(t2[k], 1.061405429f, -1.453152027f);
        p = fmaf(t2[k], p, 1.421413741f);
        p = fmaf(t2[k], p, -0.284496736f);
        p = fmaf(t2[k], p, 0.254829592f);
        p *= t2[k];
        e2[k] = copysignf(fmaf(-p, g2[k], 1.0f), x2[k]);
    }
    // ---- stage 5: Gaussian factor + accumulate ----
    float acc = 0.f;
    float E[VB];
    #pragma unroll
    for (int k = 0; k < VB; ++k) E[k] = __expf(-q[k] * q[k]);
    #pragma unroll
    for (int k = 0; k < VB; ++k) {
        const float contrib = (C * E[k]) * (e1[k] - e2[k]) * inv_s[k];
        if (MIXED) acc += (ibase + k < j) ? contrib : 0.f;  // mask kills i>=j and diag NaN
        else       acc += contrib;                          // pure: i<j guaranteed
    }
    return acc;
}

// ---------------- fused kernel: pair integral + event intensity ----------------
__global__ __launch_bounds__(BLK) void fused_kernel(
        const int* __restrict__ eu, const int* __restrict__ ev,
        const float* __restrict__ et,
        const float2* __restrict__ z0, const float2* __restrict__ v0,
        const float* __restrict__ beta_p, const float* __restrict__ t0_p,
        const float* __restrict__ tn_p,
        float* __restrict__ ev_partials, float* __restrict__ pair_partials,
        int nE) {
    const int bid = blockIdx.x;
    const bool is_ev = (bid % 5 == 0);

    if (is_ev) {
        // ----- event part: sum_e ||dz + dv*t||^2 (proven R7/R10/R11 form) -----
        const int ev_id = bid / 5;                       // [0, EV_BLOCKS)
        float acc = 0.f;
        for (int i = ev_id * BLK + threadIdx.x; i < nE; i += EV_BLOCKS * BLK) {
            const int a = eu[i];
            const int bw = ev[i];
            const float t = et[i];
            const float2 za = z0[a], zb = z0[bw];
            const float2 va = v0[a], vb = v0[bw];
            const float dx = fmaf(va.x - vb.x, t, za.x - zb.x);
            const float dy = fmaf(va.y - vb.y, t, za.y - zb.y);
            acc += fmaf(dx, dx, dy * dy);
        }
        const float r = block_reduce_f(acc);
        if (threadIdx.x == 0) ev_partials[ev_id] = r;
    } else {
        // ----- pair part: direct upper-triangle tile enumeration -----
        const int pair_id = bid - (bid / 5 + 1);         // [0, PAIR_BLOCKS)
        const float b  = beta_p[0];
        const float t0 = t0_p[0];
        const float tn = tn_p[0];
        const float C  = -0.88622692545275801365f * __expf(b);   // -sqrt(pi)/2 * e^b

        // invert triangular index: cum(jg) = 16*jg*(jg+1) blocks before group jg
        const int P = pair_id >> 4;                      // [0, 272)
        int jg = (int)((sqrtf((float)(4 * P + 1)) - 1.0f) * 0.5f);
        while ((jg + 1) * (jg + 2) <= P) ++jg;           // integer correction
        while (jg * (jg + 1) > P) --jg;
        const int ic    = pair_id - 16 * jg * (jg + 1);  // [0, 32*(jg+1))
        const int ibase = ic << 3;                       // 8 consecutive i
        const int j     = (jg << 8) | threadIdx.x;       // per-lane, coalesced

        float acc;
        if (ic < 32 * jg) acc = pair_body<false>(z0, v0, ibase, j, t0, tn, C);  // pure: i<j always
        else              acc = pair_body<true >(z0, v0, ibase, j, t0, tn, C);  // straddles diagonal

        const float r = block_reduce_f(acc);
        if (threadIdx.x == 0) pair_partials[pair_id] = r;
    }
}

// ---------------- final combine (double precision, deterministic) ----------------
__global__ void final_kernel(const float* __restrict__ evp, const float* __restrict__ pp,
                             const float* __restrict__ beta_p, float* __restrict__ out,
                             int nE) {
    __shared__ double sd[BLK];
    double se = 0.0;
    for (int i = threadIdx.x; i < EV_BLOCKS; i += BLK) se += (double)evp[i];
    double sp = 0.0;
    for (int i = threadIdx.x; i < PAIR_BLOCKS; i += BLK) sp += (double)pp[i];
    sd[threadIdx.x] = se + sp;   // (sum d2) + non_event_intensity
    __syncthreads();
    for (int s = BLK / 2; s > 0; s >>= 1) {
        if (threadIdx.x < s) sd[threadIdx.x] += sd[threadIdx.x + s];
        __syncthreads();
    }
    if (threadIdx.x == 0) {
        out[0] = (float)((double)nE * (double)beta_p[0] - sd[0]);
    }
}

extern "C" void kernel_launch(void* const* d_in, const int* in_sizes, int n_in,
                              void* d_out, int out_size, void* d_ws, size_t ws_size,
                              hipStream_t stream) {
    const int*    eu   = (const int*)d_in[0];
    const int*    ev   = (const int*)d_in[1];
    const float*  et   = (const float*)d_in[2];
    const float*  t0   = (const float*)d_in[3];
    const float*  tn   = (const float*)d_in[4];
    const float*  beta = (const float*)d_in[5];
    const float2* z0   = (const float2*)d_in[6];
    const float2* v0   = (const float2*)d_in[7];
    float* out = (float*)d_out;
    const int nE = in_sizes[0];

    float* ev_partials   = (float*)d_ws;                  // EV_BLOCKS floats
    float* pair_partials = ev_partials + EV_BLOCKS;       // PAIR_BLOCKS floats

    fused_kernel<<<TOTAL_BLOCKS, BLK, 0, stream>>>(eu, ev, et, z0, v0, beta, t0, tn,
                                                   ev_partials, pair_partials, nE);
    final_kernel<<<1, BLK, 0, stream>>>(ev_partials, pair_partials, beta, out, nE);
}